// Round 11
// baseline (209.363 us; speedup 1.0000x reference)
//
#include <hip/hip_runtime.h>

#define BINS  30
#define NROWS 8192
#define NCOLS 2048
#define YSLICES 64                       // grid.y
#define ROWS_PER_BLK 128                 // NROWS / YSLICES
#define FIXED_SCALE 16384.0f             // 2^14 fixed point for bce
#define CNT_SHIFT   24                   // count in [24:31], sum in [0:24)
#define SUM_MASK    ((1u << CNT_SHIFT) - 1)

// ws layout (bytes), all plain-stored before read -> no zeroing needed:
//   part : u32[YSLICES][BINS][NCOLS]   (15.7 MB)
//   cnt  : float[BINS][NCOLS]
//   bsum : float[BINS][NCOLS]
//   blockPart: float[8]
#define WS_PART  0
#define WS_CNT   (YSLICES * BINS * NCOLS * 4)
#define WS_BSUM  (WS_CNT + BINS * NCOLS * 4)
#define WS_BPART (WS_BSUM + BINS * NCOLS * 4)

// ---------------------------------------------------------------------------
// Per-element update of a PRIVATE register histogram (no LDS, no atomics).
// Packed u32 cell: count in bits [24:31] (<=128/thread), bce*2^14 in [0:24)
// (max 128*6.5*2^14 = 13.6M < 2^24, no carry).
// 30-way predicated add: constant indices after unroll -> stays in VGPRs;
// per bin: v_cmp_eq + v_cndmask + v_add (3 VALU), 30 independent chains.
// ---------------------------------------------------------------------------
__device__ __forceinline__ void accum(float p, int t, unsigned int (&h)[BINS])
{
    float pp = __int_as_float(__float_as_int(p) ^ (t << 31));   // t? -p : p
    float e  = __expf(-fabsf(pp));                              // exp(-|p'|)
    float d  = 1.0f + e;
    float r1 = __builtin_amdgcn_rcpf(d);
    float g  = (pp >= 0.0f) ? r1 : e * r1;                      // sigmoid(p')
    int   b  = (int)(g * 30.0f);
    b = b > (BINS - 1) ? (BINS - 1) : b;
    float bce = fmaxf(pp, 0.0f) + __logf(d);                    // softplus(p')
    unsigned int pk = (1u << CNT_SHIFT)
        | (unsigned int)(bce * FIXED_SCALE + 0.5f);
    #pragma unroll
    for (int bb = 0; bb < BINS; ++bb)
        h[bb] += (b == bb) ? pk : 0u;
}

// ---------------------------------------------------------------------------
// Kernel A: one pass, ZERO LDS, zero atomics.
// Grid (4,64) = 256 blocks x 512 threads. Thread owns ONE column
// col = blockIdx.x*512 + tid (exact coverage of [0,2048), no overlap —
// R10's crash was 2 cols/thread with a 512-col grid stride = OOB).
// Scalar 4B loads, coalesced 256B/wave; batch-4-row depth-2 pipeline
// pinned by sched_barrier(0). Private 30-reg packed histogram (~70 VGPR).
// Flush: 30 coalesced u32 stores -> part[y][b][col].
// ---------------------------------------------------------------------------
__global__ __launch_bounds__(512, 4) void k_main(
    const float* __restrict__ preds, const int* __restrict__ targets,
    unsigned int* __restrict__ part)
{
    const int tid = threadIdx.x;
    const int col = blockIdx.x * 512 + tid;
    const int r0  = blockIdx.y * ROWS_PER_BLK;

    unsigned int h[BINS];
    #pragma unroll
    for (int b = 0; b < BINS; ++b) h[b] = 0u;

    const float* P = preds   + (size_t)r0 * NCOLS + col;
    const int*   T = targets + (size_t)r0 * NCOLS + col;

    // prologue: batch 0 (4 rows) in flight
    float pc[4]; int tc[4];
    #pragma unroll
    for (int i = 0; i < 4; ++i) { pc[i] = P[i * NCOLS]; tc[i] = T[i * NCOLS]; }

    for (int batch = 0; batch < ROWS_PER_BLK / 4; ++batch) {    // 32 iters
        float pn[4]; int tn[4];
        if (batch < ROWS_PER_BLK / 4 - 1) {
            P += 4 * NCOLS; T += 4 * NCOLS;
            #pragma unroll
            for (int i = 0; i < 4; ++i) { pn[i] = P[i * NCOLS]; tn[i] = T[i * NCOLS]; }
        }
        __builtin_amdgcn_sched_barrier(0);   // next-batch loads stay above

        #pragma unroll
        for (int i = 0; i < 4; ++i) accum(pc[i], tc[i], h);

        #pragma unroll
        for (int i = 0; i < 4; ++i) { pc[i] = pn[i]; tc[i] = tn[i]; }
    }

    // flush: part[y][b][col], coalesced 4B stores
    unsigned int* base = part + (size_t)blockIdx.y * BINS * NCOLS + col;
    #pragma unroll
    for (int b = 0; b < BINS; ++b)
        base[(size_t)b * NCOLS] = h[b];
}

// ---------------------------------------------------------------------------
// Kernel B: wide y-slice reduction with unpack. 240 blocks x 256 threads.
// cnt max 64*128 = 8192; sum max 64*13.6M = 870M — both fit u32.
// ---------------------------------------------------------------------------
__global__ __launch_bounds__(256) void k_reduce(
    const unsigned int* __restrict__ part,
    float* __restrict__ cnt_f, float* __restrict__ bsum_f)
{
    const int id = blockIdx.x * 256 + threadIdx.x;    // 0 .. 61439
    unsigned int cnt = 0u, sm = 0u;
    #pragma unroll 16
    for (int y = 0; y < YSLICES; ++y) {
        const unsigned int v = part[(size_t)y * BINS * NCOLS + id];
        cnt += v >> CNT_SHIFT;
        sm  += v & SUM_MASK;
    }
    cnt_f[id]  = (float)cnt;
    bsum_f[id] = (float)sm * (1.0f / FIXED_SCALE);
}

// ---------------------------------------------------------------------------
// Kernel C: per-column contraction of the reduced 30x2048 table.
// col c contributes (1/(n_c*NCOLS)) * sum_b S[b,c]/acc_new[b,c].
// ---------------------------------------------------------------------------
__global__ __launch_bounds__(256) void k_colsum(
    const float* __restrict__ cnt_f, const float* __restrict__ bsum_f,
    const float* __restrict__ acc_sum, float* __restrict__ blockPart)
{
    __shared__ float wave_sums[4];
    const int tid = threadIdx.x;
    const int c   = blockIdx.x * 256 + tid;

    float colsum = 0.0f;
    int n = 0;
    #pragma unroll
    for (int b = 0; b < BINS; ++b) {
        const size_t gidx = (size_t)b * NCOLS + c;
        const float cnt = cnt_f[gidx];
        if (cnt >= 1.0f) {
            n += 1;
            float acc_new = 0.75f * acc_sum[gidx] + 0.25f * cnt;
            colsum += bsum_f[gidx] / acc_new;
        }
    }
    colsum /= (float)((n > 1 ? n : 1) * NCOLS);

    #pragma unroll
    for (int off = 32; off > 0; off >>= 1)
        colsum += __shfl_down(colsum, off, 64);
    if ((tid & 63) == 0) wave_sums[tid >> 6] = colsum;
    __syncthreads();
    if (tid == 0)
        blockPart[blockIdx.x] = wave_sums[0] + wave_sums[1] + wave_sums[2] + wave_sums[3];
}

__global__ void k_final(const float* __restrict__ blockPart, float* __restrict__ out)
{
    double s = 0.0;
    #pragma unroll
    for (int i = 0; i < 8; ++i) s += (double)blockPart[i];
    out[0] = (float)s;
}

extern "C" void kernel_launch(void* const* d_in, const int* in_sizes, int n_in,
                              void* d_out, int out_size, void* d_ws, size_t ws_size,
                              hipStream_t stream)
{
    const float* preds   = (const float*)d_in[0];
    const int*   targets = (const int*)d_in[1];
    const float* acc_sum = (const float*)d_in[2];

    unsigned int* part = (unsigned int*)((char*)d_ws + WS_PART);
    float* cnt_f       = (float*)((char*)d_ws + WS_CNT);
    float* bsum_f      = (float*)((char*)d_ws + WS_BSUM);
    float* blockPart   = (float*)((char*)d_ws + WS_BPART);

    dim3 gA(NCOLS / 512, YSLICES);       // (4, 64) = 256 blocks x 512 threads
    k_main<<<gA, 512, 0, stream>>>(preds, targets, part);

    k_reduce<<<(BINS * NCOLS) / 256, 256, 0, stream>>>(part, cnt_f, bsum_f);

    k_colsum<<<NCOLS / 256, 256, 0, stream>>>(cnt_f, bsum_f, acc_sum, blockPart);

    k_final<<<1, 1, 0, stream>>>(blockPart, (float*)d_out);
}

// Round 12
// 208.561 us; speedup vs baseline: 1.0038x; 1.0038x over previous
//
#include <hip/hip_runtime.h>

#define BINS  30
#define NROWS 8192
#define NCOLS 2048
#define COLS_PER_BLK 256                 // grid.x = 8
#define ROWS_PER_BLK 128                 // grid.y = 64
#define YSLICES 64

#define FIXED_SCALE 16384.0f             // 2^14 fixed point for bce
#define CNT_SHIFT   24                   // count in bits [24:31], sum in [0:24)
#define SUM_MASK    ((1u << CNT_SHIFT) - 1)

// ws layout (bytes), all plain-stored before read -> no zeroing needed:
//   part : u32[YSLICES][BINS][NCOLS]   (15.7 MB)
//   cnt  : float[BINS][NCOLS]
//   bsum : float[BINS][NCOLS]
#define WS_PART  0
#define WS_CNT   (YSLICES * BINS * NCOLS * 4)
#define WS_BSUM  (WS_CNT + BINS * NCOLS * 4)

// ---------------------------------------------------------------------------
// Kernel A (FROZEN from R9 — best measured: ~51 us, FETCH 65.6 MB ~= its
// effective-BW floor under harness restore contention).
// Grid (8,64) = 512 blocks, 1024 threads, 30 KB LDS -> 2 blocks/CU.
// Packed u32 LDS cell: count in [24:31] (max 128/cell/block), bce*2^14 in
// [0:24). ds_add_u32: lane owns 4 distinct cols -> 64 distinct addrs/instr,
// bank = lane%32 -> 2-way only (free). Depth-2 batches of 2 rows pinned by
// sched_barrier(0).
// ---------------------------------------------------------------------------
__global__ __launch_bounds__(1024, 8) void k_main(
    const float* __restrict__ preds, const int* __restrict__ targets,
    unsigned int* __restrict__ part)
{
    __shared__ unsigned int h[BINS * COLS_PER_BLK];   // 30720 B
    const int tid = threadIdx.x;
    for (int i = tid; i < BINS * COLS_PER_BLK; i += 1024) h[i] = 0u;
    __syncthreads();

    const int wave = tid >> 6;
    const int lane = tid & 63;
    const int colBase = blockIdx.x * COLS_PER_BLK;
    const int col0 = colBase + 4 * lane;
    const int r0   = blockIdx.y * ROWS_PER_BLK + wave * 8;   // 8 rows/wave

    const float4* P = (const float4*)(preds   + (size_t)r0 * NCOLS + col0);
    const int4*   T = (const int4*)  (targets + (size_t)r0 * NCOLS + col0);
    const int RV = NCOLS / 4;        // one row in float4 units

    // prologue: batch 0 (rows 0,1) in flight
    float4 pc0 = P[0], pc1 = P[RV];
    int4   tc0 = T[0], tc1 = T[RV];

    #pragma unroll
    for (int q = 0; q < 4; ++q) {
        float4 pn0, pn1;
        int4   tn0, tn1;
        if (q < 3) {
            P += 2 * RV; T += 2 * RV;
            pn0 = P[0]; pn1 = P[RV];
            tn0 = T[0]; tn1 = T[RV];
        }
        __builtin_amdgcn_sched_barrier(0);   // loads above may NOT sink below

        const float4 pb[2] = {pc0, pc1};
        const int4   tb[2] = {tc0, tc1};
        #pragma unroll
        for (int r = 0; r < 2; ++r) {
            const float pv[4] = {pb[r].x, pb[r].y, pb[r].z, pb[r].w};
            const int   tv[4] = {tb[r].x, tb[r].y, tb[r].z, tb[r].w};
            #pragma unroll
            for (int j = 0; j < 4; ++j) {
                float p  = pv[j];
                float pp = tv[j] ? -p : p;                    // p'
                float e  = __expf(-fabsf(pp));                // exp(-|p'|)
                float d  = 1.0f + e;
                float r1 = __builtin_amdgcn_rcpf(d);
                float g  = (pp >= 0.0f) ? r1 : e * r1;        // sigmoid(p')
                int   b  = (int)(g * 30.0f);
                b = b > (BINS - 1) ? (BINS - 1) : b;
                float bce = fmaxf(pp, 0.0f) + __logf(d);      // softplus(p')
                unsigned int pk = (1u << CNT_SHIFT)
                    | (unsigned int)(bce * FIXED_SCALE + 0.5f);
                atomicAdd(&h[b * COLS_PER_BLK + (j << 6) + lane], pk);
            }
        }
        pc0 = pn0; pc1 = pn1;
        tc0 = tn0; tc1 = tn1;
    }
    __syncthreads();

    // flush: part[y][b][colBase + r], coalesced u32 stores (unswizzle col=4l+j)
    const size_t outBase = (size_t)blockIdx.y * BINS * NCOLS + colBase;
    for (int i = tid; i < BINS * COLS_PER_BLK; i += 1024) {
        const int b = i >> 8;
        const int r = i & 255;
        const int l = r >> 2;
        const int j = r & 3;
        part[outBase + (size_t)b * NCOLS + r] = h[b * COLS_PER_BLK + (j << 6) + l];
    }
}

// ---------------------------------------------------------------------------
// Kernel B (frozen from R9): wide y-slice reduction with unpack.
// 240 blocks x 256 threads, fully coalesced.
// ---------------------------------------------------------------------------
__global__ __launch_bounds__(256) void k_reduce(
    const unsigned int* __restrict__ part,
    float* __restrict__ cnt_f, float* __restrict__ bsum_f)
{
    const int id = blockIdx.x * 256 + threadIdx.x;    // 0 .. 61439
    unsigned int cnt = 0u, sm = 0u;
    #pragma unroll 16
    for (int y = 0; y < YSLICES; ++y) {
        const unsigned int v = part[(size_t)y * BINS * NCOLS + id];
        cnt += v >> CNT_SHIFT;
        sm  += v & SUM_MASK;
    }
    cnt_f[id]  = (float)cnt;
    bsum_f[id] = (float)sm * (1.0f / FIXED_SCALE);
}

// ---------------------------------------------------------------------------
// Kernel C (fused colsum + final): ONE block x 1024 threads.
// Thread handles cols c = tid and tid+1024; per column:
//   colsum_c = (1/(n_c*NCOLS)) * sum_b S[b,c]/acc_new[b,c]
// Reads 0.74 MB coalesced (adjacent tid = adjacent c), block-reduce,
// thread 0 writes the scalar loss directly -> saves one dispatch.
// ---------------------------------------------------------------------------
__global__ __launch_bounds__(1024) void k_tail(
    const float* __restrict__ cnt_f, const float* __restrict__ bsum_f,
    const float* __restrict__ acc_sum, float* __restrict__ out)
{
    __shared__ float wave_sums[16];
    const int tid = threadIdx.x;

    float tsum = 0.0f;
    #pragma unroll
    for (int half = 0; half < 2; ++half) {
        const int c = tid + half * 1024;
        float colsum = 0.0f;
        int n = 0;
        #pragma unroll
        for (int b = 0; b < BINS; ++b) {
            const size_t gidx = (size_t)b * NCOLS + c;
            const float cnt = cnt_f[gidx];
            if (cnt >= 1.0f) {
                n += 1;
                float acc_new = 0.75f * acc_sum[gidx] + 0.25f * cnt;
                colsum += bsum_f[gidx] / acc_new;
            }
        }
        tsum += colsum / (float)((n > 1 ? n : 1) * NCOLS);
    }

    #pragma unroll
    for (int off = 32; off > 0; off >>= 1)
        tsum += __shfl_down(tsum, off, 64);
    if ((tid & 63) == 0) wave_sums[tid >> 6] = tsum;
    __syncthreads();
    if (tid == 0) {
        float s = 0.0f;
        #pragma unroll
        for (int w = 0; w < 16; ++w) s += wave_sums[w];
        out[0] = s;
    }
}

extern "C" void kernel_launch(void* const* d_in, const int* in_sizes, int n_in,
                              void* d_out, int out_size, void* d_ws, size_t ws_size,
                              hipStream_t stream)
{
    const float* preds   = (const float*)d_in[0];
    const int*   targets = (const int*)d_in[1];
    const float* acc_sum = (const float*)d_in[2];

    unsigned int* part = (unsigned int*)((char*)d_ws + WS_PART);
    float* cnt_f       = (float*)((char*)d_ws + WS_CNT);
    float* bsum_f      = (float*)((char*)d_ws + WS_BSUM);

    dim3 gA(NCOLS / COLS_PER_BLK, NROWS / ROWS_PER_BLK);   // (8, 64) = 512 blocks
    k_main<<<gA, 1024, 0, stream>>>(preds, targets, part);

    k_reduce<<<(BINS * NCOLS) / 256, 256, 0, stream>>>(part, cnt_f, bsum_f);

    k_tail<<<1, 1024, 0, stream>>>(cnt_f, bsum_f, acc_sum, (float*)d_out);
}